// Round 8
// baseline (1615.105 us; speedup 1.0000x reference)
//
#include <hip/hip_runtime.h>
#include <hip/hip_bf16.h>
#include <stdint.h>

typedef __bf16 bf16;
typedef __attribute__((ext_vector_type(4))) float f32x4;
typedef __attribute__((ext_vector_type(8))) bf16 bf16x8;
typedef __attribute__((ext_vector_type(4))) bf16 bf16x4;

#define AS1 __attribute__((address_space(1)))
#define AS3 __attribute__((address_space(3)))

static __device__ __forceinline__ void gload_lds16(const bf16* g, bf16* l) {
  __builtin_amdgcn_global_load_lds((const AS1 void*)g, (AS3 void*)l, 16, 0, 0);
}

#define BAR __builtin_amdgcn_s_barrier()
#define LGKM0 asm volatile("s_waitcnt lgkmcnt(0)" ::: "memory")
#define VMC(n) asm volatile("s_waitcnt vmcnt(" #n ")" ::: "memory")
#define SCHED0 __builtin_amdgcn_sched_barrier(0)

// ---- 256-thread staging: one 128x64 bf16 tile, 4 chunks/thread ----
#define STAGE_A(gsrc, dst, kt_) do {                                          \
  _Pragma("unroll") for (int s_ = 0; s_ < 4; ++s_) {                          \
    int idx_ = s_ * 256 + tid;                                                \
    int r_ = idx_ >> 3, c_ = idx_ & 7;                                        \
    gload_lds16((gsrc) + (size_t)r_ * 512 + ((kt_) << 6) + ((c_ ^ (r_ & 7)) << 3), \
                (dst) + idx_ * 8);                                            \
  }                                                                           \
} while (0)

// B fragments from L2 (K-major layout bt[k/8][col][8]); 4 col-blocks (gemm_out)
#define LOADB(ktq, NCOLX) do {                                                \
  const bf16* bp_ = Bptr + (size_t)(ktq) * ((size_t)(NCOLX) * 64);            \
  _Pragma("unroll") for (int cb_ = 0; cb_ < 4; ++cb_)                         \
  _Pragma("unroll") for (int ks_ = 0; ks_ < 2; ++ks_)                         \
    bfr[cb_][ks_] = *(const bf16x8*)(bp_ + cb_ * 128 + (size_t)ks_ * (NCOLX) * 32); \
} while (0)

// 6 col-blocks (qkv_attn, ncol=1536)
#define LOADB6(ktq) do {                                                      \
  const bf16* bp_ = Bptr + (size_t)(ktq) * 98304;                             \
  _Pragma("unroll") for (int cb_ = 0; cb_ < 6; ++cb_)                         \
  _Pragma("unroll") for (int ks_ = 0; ks_ < 2; ++ks_)                         \
    bfr[cb_][ks_] = *(const bf16x8*)(bp_ + cb_ * 128 + ks_ * 49152);          \
} while (0)

// gemm_out K-loop (round-6, verified): A dbuf in LDS, B in regs from L2.
#define KLOOP_BD(Ag, NCOLX)                                                   \
  f32x4 acc[4][4] = {};                                                       \
  bf16x8 af[4][2], bfr[4][2];                                                 \
  STAGE_A(Ag, SA0, 0);                                                        \
  LOADB(0, NCOLX);                                                            \
  VMC(8); BAR;                                                                \
  STAGE_A(Ag, SA1, 1);                                                        \
  _Pragma("unroll 2")                                                         \
  for (int kt = 0; kt < 8; ++kt) {                                            \
    bf16* Ap = (kt & 1) ? SA1 : SA0;                                          \
    _Pragma("unroll") for (int i_ = 0; i_ < 4; ++i_) {                        \
      int ra_ = wr + i_ * 16 + lr;                                            \
      _Pragma("unroll") for (int ks_ = 0; ks_ < 2; ++ks_)                     \
        af[i_][ks_] = *(const bf16x8*)(Ap + ra_ * 64 + (((ks_ * 4 + lg) ^ (ra_ & 7)) << 3)); \
    }                                                                         \
    LGKM0; SCHED0;                                                            \
    __builtin_amdgcn_s_setprio(1);                                            \
    _Pragma("unroll") for (int i_ = 0; i_ < 4; ++i_)                          \
    _Pragma("unroll") for (int j_ = 0; j_ < 4; ++j_)                          \
    _Pragma("unroll") for (int ks_ = 0; ks_ < 2; ++ks_)                       \
      acc[i_][j_] = __builtin_amdgcn_mfma_f32_16x16x32_bf16(                  \
          af[i_][ks_], bfr[j_][ks_], acc[i_][j_], 0, 0, 0);                   \
    __builtin_amdgcn_s_setprio(0);                                            \
    if (kt < 7) LOADB(kt + 1, NCOLX);                                         \
    if (kt < 7) { VMC(8); }                                                   \
    BAR;                                                                      \
    if (kt < 6) STAGE_A(Ag, Ap, kt + 2);                                      \
  }

// ---------------- prep: roll + reorder + fp32->bf16 ----------------
__global__ __launch_bounds__(256) void prep_x(const float* __restrict__ x,
                                              bf16* __restrict__ xs) {
  int m = blockIdx.x * 8 + (threadIdx.x >> 5);
  int lane = threadIdx.x & 31;
  int b = m >> 12, win = (m >> 6) & 63, t = m & 63;
  int ip = ((win >> 3) << 3) + (t >> 3);
  int jp = ((win & 7) << 3) + (t & 7);
  int io = (ip + 4) & 63, jo = (jp + 4) & 63;
  const float* src = x + ((((size_t)(b << 6) + io) << 6) + jo) * 512;
  bf16* dst = xs + ((size_t)m << 9);
  #pragma unroll
  for (int c0 = 0; c0 < 512; c0 += 128) {
    int c = c0 + lane * 4;
    float4 v = *(const float4*)(src + c);
    bf16x4 o = { (bf16)v.x, (bf16)v.y, (bf16)v.z, (bf16)v.w };
    *(bf16x4*)(dst + c) = o;
  }
}

// Weights -> bf16, K-major-grouped bt[k/8][col][8]. q-scale folded.
// wqkv cols permuted head-major: col2 = h*96 + part*32 + d. wout unpermuted.
__global__ __launch_bounds__(256) void prep_w(const float* __restrict__ wqkv,
                                              const float* __restrict__ wout,
                                              bf16* __restrict__ wqkv_bt,
                                              bf16* __restrict__ wout_bt) {
  int r = blockIdx.x * 8 + (threadIdx.x >> 5);
  int lane = threadIdx.x & 31;
  const float* src;
  bf16* dstb;
  int ncol, col;
  float sc = 1.0f;
  if (r < 1536) {
    int part = r >> 9, h = (r >> 5) & 15, d = r & 31;
    src = wqkv + (size_t)r * 512; dstb = wqkv_bt; ncol = 1536;
    col = h * 96 + part * 32 + d;
    if (part == 0) sc = 0.17677669529663689f;
  } else {
    src = wout + (size_t)(r - 1536) * 512; dstb = wout_bt; ncol = 512; col = r - 1536;
  }
  #pragma unroll
  for (int kb = lane; kb < 64; kb += 32) {
    float4 v0 = *(const float4*)(src + kb * 8);
    float4 v1 = *(const float4*)(src + kb * 8 + 4);
    bf16x8 o = { (bf16)(v0.x * sc), (bf16)(v0.y * sc), (bf16)(v0.z * sc), (bf16)(v0.w * sc),
                 (bf16)(v1.x * sc), (bf16)(v1.y * sc), (bf16)(v1.z * sc), (bf16)(v1.w * sc) };
    *(bf16x8*)(dstb + ((size_t)kb * ncol + col) * 8) = o;
  }
}

__global__ __launch_bounds__(256) void prep_bias(const float* __restrict__ pos,
                                                 float* __restrict__ bias4) {
  for (int idx = threadIdx.x; idx < 4 * 4096; idx += 256) {
    int ty = idx >> 12, ij = idx & 4095;
    int i = ij >> 6, j = ij & 63;
    int rx = ((j >> 3) - (i >> 3)) + 7;
    int ry = ((j & 7) - (i & 7)) + 7;
    float v = pos[rx * 15 + ry];
    if ((ty & 1) && (((i ^ j) >> 5) & 1)) v = -1e30f;
    if ((ty & 2) && (((i ^ j) >> 2) & 1)) v = -1e30f;
    bias4[idx] = v;
  }
}

// ---------------- fused QKV-GEMM + window attention ----------------
// Block: 128 tokens (2 windows) x 2 heads; 256 thr = 4 waves = 4 (win,head)
// units. LDS = union{A-stage 32KB, E 4x8KB} = 32KB -> 4 blocks/CU (16 waves).
// q|k restaged via private 8KB LDS (swizzled); v goes acc->regs via same-lr
// shuffles (no LDS); P reuses the dead q|k region.
__global__ __launch_bounds__(256, 4) void qkv_attn(
    const bf16* __restrict__ xs, const bf16* __restrict__ wb2,
    const float* __restrict__ bias4, bf16* __restrict__ ao) {
  __shared__ union { bf16 A[2][8192]; bf16 E[4][4096]; } sm;
  bf16* SA0 = sm.A[0]; bf16* SA1 = sm.A[1];

  const int tid = threadIdx.x, wave = tid >> 6, lane = tid & 63;
  const int ww = wave & 1, wh = wave >> 1;     // window-in-tile, head-in-pair
  const int lr = lane & 15, lg = lane >> 4;

  int bid = blockIdx.x;
  bid = (bid & 7) * 512 + (bid >> 3);          // XCD swizzle (4096 = 8*512)
  const int mt = bid >> 3, hp = bid & 7;
  const int h = hp * 2 + wh;

  const bf16* Ag = xs + ((size_t)mt * 128) * 512;
  const bf16* Bptr = wb2 + (((size_t)lg * 1536) + h * 96 + lr) * 8;

  f32x4 acc[4][6] = {};
  bf16x8 af[4][2], bfr[6][2];

  // K-loop: invariant entering kt: Bf(kt)[12] + Ast(kt+1)[4] in flight.
  STAGE_A(Ag, SA0, 0);
  LOADB6(0);
  VMC(12); BAR;                 // drain Ast(0) (VMC before publishing BAR)
  STAGE_A(Ag, SA1, 1);
  #pragma unroll 2
  for (int kt = 0; kt < 8; ++kt) {
    bf16* Ap = (kt & 1) ? SA1 : SA0;
    #pragma unroll
    for (int i_ = 0; i_ < 4; ++i_) {
      int ra_ = ww * 64 + i_ * 16 + lr;
      #pragma unroll
      for (int ks_ = 0; ks_ < 2; ++ks_)
        af[i_][ks_] = *(const bf16x8*)(Ap + ra_ * 64 + (((ks_ * 4 + lg) ^ (ra_ & 7)) << 3));
    }
    LGKM0; SCHED0;
    __builtin_amdgcn_s_setprio(1);
    #pragma unroll
    for (int i_ = 0; i_ < 4; ++i_)
      #pragma unroll
      for (int j_ = 0; j_ < 6; ++j_)
        #pragma unroll
        for (int ks_ = 0; ks_ < 2; ++ks_)
          acc[i_][j_] = __builtin_amdgcn_mfma_f32_16x16x32_bf16(
              af[i_][ks_], bfr[j_][ks_], acc[i_][j_], 0, 0, 0);
    __builtin_amdgcn_s_setprio(0);
    if (kt < 7) { LOADB6(kt + 1); VMC(12); }  // drain Ast(kt+1), keep B(kt+1)
    BAR;                                       // publish A(kt+1)
    if (kt < 6) STAGE_A(Ag, Ap, kt + 2);
  }
  // ---- per-wave epilogue ----
  bf16* Ew = sm.E[wave];
  // 1) q|k (slab cols 0..63) -> row-major [64][64], XOR-swizzled
  #pragma unroll
  for (int i = 0; i < 4; ++i)
    #pragma unroll
    for (int r = 0; r < 4; ++r) {
      int row = i * 16 + (lg << 2) + r;        // token
      #pragma unroll
      for (int j = 0; j < 4; ++j) {
        int c = j * 16 + lr;
        Ew[row * 64 + (c ^ ((row & 7) << 3))] = (bf16)acc[i][j][r];
      }
    }
  // 2) v (slab cols 64..95): acc -> PV B-fragments via same-lr shuffles.
  // vf[kk][nj] lane(lr,lg) = v[tok=32kk+8lg+m][d=16nj+lr], m=0..7;
  // source: acc[2kk+(lg>>1)][4+nj][m&3] of lane lr+16*((2lg+(m>>2))&3).
  bf16x8 vf[2][2];
  {
    const int s0 = lr + 16 * ((2 * lg) & 3);
    const int s1 = lr + 16 * ((2 * lg + 1) & 3);
    const bool lo = (lg < 2);
    #pragma unroll
    for (int kk = 0; kk < 2; ++kk)
      #pragma unroll
      for (int nj = 0; nj < 2; ++nj) {
        float f[8];
        #pragma unroll
        for (int c = 0; c < 4; ++c) {
          float a0 = __shfl(acc[2 * kk][4 + nj][c], s0);
          float a1 = __shfl(acc[2 * kk + 1][4 + nj][c], s0);
          f[c] = lo ? a0 : a1;
          float b0 = __shfl(acc[2 * kk][4 + nj][c], s1);
          float b1 = __shfl(acc[2 * kk + 1][4 + nj][c], s1);
          f[4 + c] = lo ? b0 : b1;
        }
        vf[kk][nj] = (bf16x8){ (bf16)f[0], (bf16)f[1], (bf16)f[2], (bf16)f[3],
                               (bf16)f[4], (bf16)f[5], (bf16)f[6], (bf16)f[7] };
      }
  }
  LGKM0; SCHED0;
  // 3) QK^T
  bf16x8 qf[4], kf[4];
  #pragma unroll
  for (int i = 0; i < 4; ++i) {
    int ra = i * 16 + lr;
    qf[i] = *(const bf16x8*)(Ew + ra * 64 + (((lg << 3)) ^ ((ra & 7) << 3)));
    kf[i] = *(const bf16x8*)(Ew + ra * 64 + ((32 + (lg << 3)) ^ ((ra & 7) << 3)));
  }
  f32x4 s[4][4] = {};
  #pragma unroll
  for (int i = 0; i < 4; ++i)
    #pragma unroll
    for (int j = 0; j < 4; ++j)
      s[i][j] = __builtin_amdgcn_mfma_f32_16x16x32_bf16(qf[i], kf[j], s[i][j], 0, 0, 0);

  const int gw = mt * 2 + ww;
  const int win = gw & 63;
  const int ty = ((win >= 56) ? 1 : 0) | (((win & 7) == 7) ? 2 : 0);
  const float* bt = bias4 + ty * 4096;
  #pragma unroll
  for (int i = 0; i < 4; ++i)
    #pragma unroll
    for (int r = 0; r < 4; ++r) {
      int row = i * 16 + (lg << 2) + r;
      #pragma unroll
      for (int j = 0; j < 4; ++j)
        s[i][j][r] += bt[row * 64 + j * 16 + lr];
    }
  // 4) wave-parallel softmax; P into the dead q|k region (swizzled)
  #pragma unroll
  for (int i = 0; i < 4; ++i)
    #pragma unroll
    for (int r = 0; r < 4; ++r) {
      float mx = fmaxf(fmaxf(s[i][0][r], s[i][1][r]), fmaxf(s[i][2][r], s[i][3][r]));
      mx = fmaxf(mx, __shfl_xor(mx, 1));
      mx = fmaxf(mx, __shfl_xor(mx, 2));
      mx = fmaxf(mx, __shfl_xor(mx, 4));
      mx = fmaxf(mx, __shfl_xor(mx, 8));
      float sum = 0.f;
      #pragma unroll
      for (int j = 0; j < 4; ++j) { s[i][j][r] = __expf(s[i][j][r] - mx); sum += s[i][j][r]; }
      sum += __shfl_xor(sum, 1);
      sum += __shfl_xor(sum, 2);
      sum += __shfl_xor(sum, 4);
      sum += __shfl_xor(sum, 8);
      float inv = 1.0f / sum;
      int row = i * 16 + (lg << 2) + r;
      #pragma unroll
      for (int j = 0; j < 4; ++j) {
        int c = j * 16 + lr;
        Ew[row * 64 + (c ^ ((row & 7) << 3))] = (bf16)(s[i][j][r] * inv);
      }
    }
  LGKM0; SCHED0;
  // 5) PV: pa from LDS, v from registers
  f32x4 o[4][2] = {};
  #pragma unroll
  for (int kk = 0; kk < 2; ++kk)
    #pragma unroll
    for (int mi = 0; mi < 4; ++mi) {
      int ra = mi * 16 + lr;
      bf16x8 pa = *(const bf16x8*)(Ew + ra * 64 + ((kk * 32 + (lg << 3)) ^ ((ra & 7) << 3)));
      #pragma unroll
      for (int nj = 0; nj < 2; ++nj)
        o[mi][nj] = __builtin_amdgcn_mfma_f32_16x16x32_bf16(pa, vf[kk][nj], o[mi][nj], 0, 0, 0);
    }
  // 6) ao rows (K-contiguous for out-proj)
  bf16* dst = ao + ((size_t)(mt * 128 + ww * 64)) * 512 + h * 32;
  #pragma unroll
  for (int mi = 0; mi < 4; ++mi)
    #pragma unroll
    for (int r = 0; r < 4; ++r) {
      int t = mi * 16 + (lg << 2) + r;
      #pragma unroll
      for (int nj = 0; nj < 2; ++nj)
        dst[(size_t)t * 512 + nj * 16 + lr] = (bf16)o[mi][nj][r];
    }
}

// ---------------- out-proj GEMM + bias + inverse roll ----------------
__global__ __launch_bounds__(256, 3) void gemm_out(
    const bf16* __restrict__ ao, const bf16* __restrict__ wob,
    const float* __restrict__ bout, float* __restrict__ out) {
  __shared__ bf16 SA[2][8192];
  bf16* SA0 = SA[0]; bf16* SA1 = SA[1];

  const int tid = threadIdx.x, wave = tid >> 6, lane = tid & 63;
  int bid = blockIdx.x;
  bid = (bid & 7) * 256 + (bid >> 3);          // XCD swizzle (2048 = 8*256)
  const int mt = bid >> 2, nt = bid & 3;
  const bf16* Ag = ao + ((size_t)mt * 128) * 512;
  const int wr = (wave >> 1) << 6, wc = (wave & 1) << 6;
  const int lr = lane & 15, lg = lane >> 4;
  const bf16* Bptr = wob + (((size_t)lg * 512) + nt * 128 + wc + lr) * 8;

  KLOOP_BD(Ag, 512)

  float bv[4];
  #pragma unroll
  for (int j = 0; j < 4; ++j) bv[j] = bout[nt * 128 + wc + j * 16 + lr];
  #pragma unroll
  for (int i = 0; i < 4; ++i)
    #pragma unroll
    for (int r = 0; r < 4; ++r) {
      int m = (mt << 7) + wr + i * 16 + (lg << 2) + r;
      int b = m >> 12, win = (m >> 6) & 63, t = m & 63;
      int ip = ((win >> 3) << 3) + (t >> 3);
      int jp = ((win & 7) << 3) + (t & 7);
      int io = (ip + 4) & 63, jo = (jp + 4) & 63;
      float* orow = out + ((((size_t)(b << 6) + io) << 6) + jo) * 512 + nt * 128 + wc;
      #pragma unroll
      for (int j = 0; j < 4; ++j)
        orow[j * 16 + lr] = acc[i][j][r] + bv[j];
    }
}

extern "C" void kernel_launch(void* const* d_in, const int* in_sizes, int n_in,
                              void* d_out, int out_size, void* d_ws, size_t ws_size,
                              hipStream_t stream) {
  const float* x    = (const float*)d_in[0];
  const float* wqkv = (const float*)d_in[1];
  const float* pos  = (const float*)d_in[2];
  const float* wout = (const float*)d_in[3];
  const float* bout = (const float*)d_in[4];
  float* out = (float*)d_out;

  char* ws = (char*)d_ws;
  bf16* xs      = (bf16*)(ws);                 // 64 MB
  bf16* ao      = (bf16*)(ws + 67108864);      // 64 MB
  bf16* wqkv_bt = (bf16*)(ws + 268435456);
  bf16* wout_bt = (bf16*)(ws + 270008320);
  float* bias4  = (float*)(ws + 270532608);

  prep_x<<<dim3(8192), dim3(256), 0, stream>>>(x, xs);
  prep_w<<<dim3(256), dim3(256), 0, stream>>>(wqkv, wout, wqkv_bt, wout_bt);
  prep_bias<<<dim3(1), dim3(256), 0, stream>>>(pos, bias4);
  qkv_attn<<<dim3(4096), dim3(256), 0, stream>>>(xs, wqkv_bt, bias4, ao);
  gemm_out<<<dim3(2048), dim3(256), 0, stream>>>(ao, wout_bt, bout, out);
}

// Round 9
// 261.790 us; speedup vs baseline: 6.1695x; 6.1695x over previous
//
#include <hip/hip_runtime.h>
#include <hip/hip_bf16.h>
#include <stdint.h>

typedef __bf16 bf16;
typedef __attribute__((ext_vector_type(4))) float f32x4;
typedef __attribute__((ext_vector_type(8))) bf16 bf16x8;
typedef __attribute__((ext_vector_type(4))) bf16 bf16x4;

#define AS1 __attribute__((address_space(1)))
#define AS3 __attribute__((address_space(3)))

static __device__ __forceinline__ void gload_lds16(const bf16* g, bf16* l) {
  __builtin_amdgcn_global_load_lds((const AS1 void*)g, (AS3 void*)l, 16, 0, 0);
}

#define BAR __builtin_amdgcn_s_barrier()
#define LGKM0 asm volatile("s_waitcnt lgkmcnt(0)" ::: "memory")
#define VMC(n) asm volatile("s_waitcnt vmcnt(" #n ")" ::: "memory")
#define SCHED0 __builtin_amdgcn_sched_barrier(0)

// ---- 256-thread staging: one 128x64 bf16 tile, 4 chunks/thread ----
#define STAGE_A(gsrc, dst, kt_) do {                                          \
  _Pragma("unroll") for (int s_ = 0; s_ < 4; ++s_) {                          \
    int idx_ = s_ * 256 + tid;                                                \
    int r_ = idx_ >> 3, c_ = idx_ & 7;                                        \
    gload_lds16((gsrc) + (size_t)r_ * 512 + ((kt_) << 6) + ((c_ ^ (r_ & 7)) << 3), \
                (dst) + idx_ * 8);                                            \
  }                                                                           \
} while (0)

// B fragments from L2 (K-major layout bt[k/8][col][8]); 4 col-blocks (gemm_out)
#define LOADB(ktq, NCOLX) do {                                                \
  const bf16* bp_ = Bptr + (size_t)(ktq) * ((size_t)(NCOLX) * 64);            \
  _Pragma("unroll") for (int cb_ = 0; cb_ < 4; ++cb_)                         \
  _Pragma("unroll") for (int ks_ = 0; ks_ < 2; ++ks_)                         \
    bfr[cb_][ks_] = *(const bf16x8*)(bp_ + cb_ * 128 + (size_t)ks_ * (NCOLX) * 32); \
} while (0)

// 6 col-blocks (qkv_attn, ncol=1536)
#define LOADB6(ktq) do {                                                      \
  const bf16* bp_ = Bptr + (size_t)(ktq) * 98304;                             \
  _Pragma("unroll") for (int cb_ = 0; cb_ < 6; ++cb_)                         \
  _Pragma("unroll") for (int ks_ = 0; ks_ < 2; ++ks_)                         \
    bfr[cb_][ks_] = *(const bf16x8*)(bp_ + cb_ * 128 + ks_ * 49152);          \
} while (0)

// gemm_out K-loop (round-6, verified): A dbuf in LDS, B in regs from L2.
#define KLOOP_BD(Ag, NCOLX)                                                   \
  f32x4 acc[4][4] = {};                                                       \
  bf16x8 af[4][2], bfr[4][2];                                                 \
  STAGE_A(Ag, SA0, 0);                                                        \
  LOADB(0, NCOLX);                                                            \
  VMC(8); BAR;                                                                \
  STAGE_A(Ag, SA1, 1);                                                        \
  _Pragma("unroll 2")                                                         \
  for (int kt = 0; kt < 8; ++kt) {                                            \
    bf16* Ap = (kt & 1) ? SA1 : SA0;                                          \
    _Pragma("unroll") for (int i_ = 0; i_ < 4; ++i_) {                        \
      int ra_ = wr + i_ * 16 + lr;                                            \
      _Pragma("unroll") for (int ks_ = 0; ks_ < 2; ++ks_)                     \
        af[i_][ks_] = *(const bf16x8*)(Ap + ra_ * 64 + (((ks_ * 4 + lg) ^ (ra_ & 7)) << 3)); \
    }                                                                         \
    LGKM0; SCHED0;                                                            \
    __builtin_amdgcn_s_setprio(1);                                            \
    _Pragma("unroll") for (int i_ = 0; i_ < 4; ++i_)                          \
    _Pragma("unroll") for (int j_ = 0; j_ < 4; ++j_)                          \
    _Pragma("unroll") for (int ks_ = 0; ks_ < 2; ++ks_)                       \
      acc[i_][j_] = __builtin_amdgcn_mfma_f32_16x16x32_bf16(                  \
          af[i_][ks_], bfr[j_][ks_], acc[i_][j_], 0, 0, 0);                   \
    __builtin_amdgcn_s_setprio(0);                                            \
    if (kt < 7) LOADB(kt + 1, NCOLX);                                         \
    if (kt < 7) { VMC(8); }                                                   \
    BAR;                                                                      \
    if (kt < 6) STAGE_A(Ag, Ap, kt + 2);                                      \
  }

// ---------------- prep: roll + reorder + fp32->bf16 ----------------
__global__ __launch_bounds__(256) void prep_x(const float* __restrict__ x,
                                              bf16* __restrict__ xs) {
  int m = blockIdx.x * 8 + (threadIdx.x >> 5);
  int lane = threadIdx.x & 31;
  int b = m >> 12, win = (m >> 6) & 63, t = m & 63;
  int ip = ((win >> 3) << 3) + (t >> 3);
  int jp = ((win & 7) << 3) + (t & 7);
  int io = (ip + 4) & 63, jo = (jp + 4) & 63;
  const float* src = x + ((((size_t)(b << 6) + io) << 6) + jo) * 512;
  bf16* dst = xs + ((size_t)m << 9);
  #pragma unroll
  for (int c0 = 0; c0 < 512; c0 += 128) {
    int c = c0 + lane * 4;
    float4 v = *(const float4*)(src + c);
    bf16x4 o = { (bf16)v.x, (bf16)v.y, (bf16)v.z, (bf16)v.w };
    *(bf16x4*)(dst + c) = o;
  }
}

// Weights -> bf16, K-major-grouped bt[k/8][col][8]. q-scale folded.
// wqkv cols permuted head-major: col2 = h*96 + part*32 + d. wout unpermuted.
__global__ __launch_bounds__(256) void prep_w(const float* __restrict__ wqkv,
                                              const float* __restrict__ wout,
                                              bf16* __restrict__ wqkv_bt,
                                              bf16* __restrict__ wout_bt) {
  int r = blockIdx.x * 8 + (threadIdx.x >> 5);
  int lane = threadIdx.x & 31;
  const float* src;
  bf16* dstb;
  int ncol, col;
  float sc = 1.0f;
  if (r < 1536) {
    int part = r >> 9, h = (r >> 5) & 15, d = r & 31;
    src = wqkv + (size_t)r * 512; dstb = wqkv_bt; ncol = 1536;
    col = h * 96 + part * 32 + d;
    if (part == 0) sc = 0.17677669529663689f;
  } else {
    src = wout + (size_t)(r - 1536) * 512; dstb = wout_bt; ncol = 512; col = r - 1536;
  }
  #pragma unroll
  for (int kb = lane; kb < 64; kb += 32) {
    float4 v0 = *(const float4*)(src + kb * 8);
    float4 v1 = *(const float4*)(src + kb * 8 + 4);
    bf16x8 o = { (bf16)(v0.x * sc), (bf16)(v0.y * sc), (bf16)(v0.z * sc), (bf16)(v0.w * sc),
                 (bf16)(v1.x * sc), (bf16)(v1.y * sc), (bf16)(v1.z * sc), (bf16)(v1.w * sc) };
    *(bf16x8*)(dstb + ((size_t)kb * ncol + col) * 8) = o;
  }
}

__global__ __launch_bounds__(256) void prep_bias(const float* __restrict__ pos,
                                                 float* __restrict__ bias4) {
  for (int idx = threadIdx.x; idx < 4 * 4096; idx += 256) {
    int ty = idx >> 12, ij = idx & 4095;
    int i = ij >> 6, j = ij & 63;
    int rx = ((j >> 3) - (i >> 3)) + 7;
    int ry = ((j & 7) - (i & 7)) + 7;
    float v = pos[rx * 15 + ry];
    if ((ty & 1) && (((i ^ j) >> 5) & 1)) v = -1e30f;
    if ((ty & 2) && (((i ^ j) >> 2) & 1)) v = -1e30f;
    bias4[idx] = v;
  }
}

// ---------------- fused QKV-GEMM + window attention ----------------
// Block: 128 tokens (2 windows) x 2 heads; 256 thr = 4 waves = 4 (win,head)
// units. LDS = union{A-stage 32KB, E 4x8KB} = 32KB.
// __launch_bounds__(256,2): 256-VGPR budget -> NO SPILL (r8 lesson: (256,4)
// capped at 128 and acc[4][6]+bfr+af+vf ~144 data regs spilled -> 7GB scratch).
__global__ __launch_bounds__(256, 2) void qkv_attn(
    const bf16* __restrict__ xs, const bf16* __restrict__ wb2,
    const float* __restrict__ bias4, bf16* __restrict__ ao) {
  __shared__ union { bf16 A[2][8192]; bf16 E[4][4096]; } sm;
  bf16* SA0 = sm.A[0]; bf16* SA1 = sm.A[1];

  const int tid = threadIdx.x, wave = tid >> 6, lane = tid & 63;
  const int ww = wave & 1, wh = wave >> 1;     // window-in-tile, head-in-pair
  const int lr = lane & 15, lg = lane >> 4;

  int bid = blockIdx.x;
  bid = (bid & 7) * 512 + (bid >> 3);          // XCD swizzle (4096 = 8*512)
  const int mt = bid >> 3, hp = bid & 7;
  const int h = hp * 2 + wh;

  const bf16* Ag = xs + ((size_t)mt * 128) * 512;
  const bf16* Bptr = wb2 + (((size_t)lg * 1536) + h * 96 + lr) * 8;

  f32x4 acc[4][6] = {};
  bf16x8 af[4][2], bfr[6][2];

  // K-loop: invariant entering kt: Bf(kt)[12] + Ast(kt+1)[4] in flight.
  STAGE_A(Ag, SA0, 0);
  LOADB6(0);
  VMC(12); BAR;                 // drain Ast(0) (VMC before publishing BAR)
  STAGE_A(Ag, SA1, 1);
  #pragma unroll 2
  for (int kt = 0; kt < 8; ++kt) {
    bf16* Ap = (kt & 1) ? SA1 : SA0;
    #pragma unroll
    for (int i_ = 0; i_ < 4; ++i_) {
      int ra_ = ww * 64 + i_ * 16 + lr;
      #pragma unroll
      for (int ks_ = 0; ks_ < 2; ++ks_)
        af[i_][ks_] = *(const bf16x8*)(Ap + ra_ * 64 + (((ks_ * 4 + lg) ^ (ra_ & 7)) << 3));
    }
    LGKM0; SCHED0;
    __builtin_amdgcn_s_setprio(1);
    #pragma unroll
    for (int i_ = 0; i_ < 4; ++i_)
      #pragma unroll
      for (int j_ = 0; j_ < 6; ++j_)
        #pragma unroll
        for (int ks_ = 0; ks_ < 2; ++ks_)
          acc[i_][j_] = __builtin_amdgcn_mfma_f32_16x16x32_bf16(
              af[i_][ks_], bfr[j_][ks_], acc[i_][j_], 0, 0, 0);
    __builtin_amdgcn_s_setprio(0);
    if (kt < 7) { LOADB6(kt + 1); VMC(12); }  // drain Ast(kt+1), keep B(kt+1)
    BAR;                                       // publish A(kt+1)
    if (kt < 6) STAGE_A(Ag, Ap, kt + 2);
  }
  // ---- per-wave epilogue ----
  bf16* Ew = sm.E[wave];
  // 1) q|k (slab cols 0..63) -> row-major [64][64], XOR-swizzled
  #pragma unroll
  for (int i = 0; i < 4; ++i)
    #pragma unroll
    for (int r = 0; r < 4; ++r) {
      int row = i * 16 + (lg << 2) + r;        // token
      #pragma unroll
      for (int j = 0; j < 4; ++j) {
        int c = j * 16 + lr;
        Ew[row * 64 + (c ^ ((row & 7) << 3))] = (bf16)acc[i][j][r];
      }
    }
  // 2) v (slab cols 64..95): acc -> PV B-fragments via same-lr shuffles.
  // vf[kk][nj] lane(lr,lg) = v[tok=32kk+8lg+m][d=16nj+lr], m=0..7;
  // source: acc[2kk+(lg>>1)][4+nj][m&3] of lane lr+16*((2lg+(m>>2))&3).
  bf16x8 vf[2][2];
  {
    const int s0 = lr + 16 * ((2 * lg) & 3);
    const int s1 = lr + 16 * ((2 * lg + 1) & 3);
    const bool lo = (lg < 2);
    #pragma unroll
    for (int kk = 0; kk < 2; ++kk)
      #pragma unroll
      for (int nj = 0; nj < 2; ++nj) {
        float f[8];
        #pragma unroll
        for (int c = 0; c < 4; ++c) {
          float a0 = __shfl(acc[2 * kk][4 + nj][c], s0);
          float a1 = __shfl(acc[2 * kk + 1][4 + nj][c], s0);
          f[c] = lo ? a0 : a1;
          float b0 = __shfl(acc[2 * kk][4 + nj][c], s1);
          float b1 = __shfl(acc[2 * kk + 1][4 + nj][c], s1);
          f[4 + c] = lo ? b0 : b1;
        }
        vf[kk][nj] = (bf16x8){ (bf16)f[0], (bf16)f[1], (bf16)f[2], (bf16)f[3],
                               (bf16)f[4], (bf16)f[5], (bf16)f[6], (bf16)f[7] };
      }
  }
  LGKM0; SCHED0;
  // 3) QK^T
  bf16x8 qf[4], kf[4];
  #pragma unroll
  for (int i = 0; i < 4; ++i) {
    int ra = i * 16 + lr;
    qf[i] = *(const bf16x8*)(Ew + ra * 64 + (((lg << 3)) ^ ((ra & 7) << 3)));
    kf[i] = *(const bf16x8*)(Ew + ra * 64 + ((32 + (lg << 3)) ^ ((ra & 7) << 3)));
  }
  f32x4 s[4][4] = {};
  #pragma unroll
  for (int i = 0; i < 4; ++i)
    #pragma unroll
    for (int j = 0; j < 4; ++j)
      s[i][j] = __builtin_amdgcn_mfma_f32_16x16x32_bf16(qf[i], kf[j], s[i][j], 0, 0, 0);

  const int gw = mt * 2 + ww;
  const int win = gw & 63;
  const int ty = ((win >= 56) ? 1 : 0) | (((win & 7) == 7) ? 2 : 0);
  const float* bt = bias4 + ty * 4096;
  #pragma unroll
  for (int i = 0; i < 4; ++i)
    #pragma unroll
    for (int r = 0; r < 4; ++r) {
      int row = i * 16 + (lg << 2) + r;
      #pragma unroll
      for (int j = 0; j < 4; ++j)
        s[i][j][r] += bt[row * 64 + j * 16 + lr];
    }
  // 4) wave-parallel softmax; P into the dead q|k region (swizzled)
  #pragma unroll
  for (int i = 0; i < 4; ++i)
    #pragma unroll
    for (int r = 0; r < 4; ++r) {
      float mx = fmaxf(fmaxf(s[i][0][r], s[i][1][r]), fmaxf(s[i][2][r], s[i][3][r]));
      mx = fmaxf(mx, __shfl_xor(mx, 1));
      mx = fmaxf(mx, __shfl_xor(mx, 2));
      mx = fmaxf(mx, __shfl_xor(mx, 4));
      mx = fmaxf(mx, __shfl_xor(mx, 8));
      float sum = 0.f;
      #pragma unroll
      for (int j = 0; j < 4; ++j) { s[i][j][r] = __expf(s[i][j][r] - mx); sum += s[i][j][r]; }
      sum += __shfl_xor(sum, 1);
      sum += __shfl_xor(sum, 2);
      sum += __shfl_xor(sum, 4);
      sum += __shfl_xor(sum, 8);
      float inv = 1.0f / sum;
      int row = i * 16 + (lg << 2) + r;
      #pragma unroll
      for (int j = 0; j < 4; ++j) {
        int c = j * 16 + lr;
        Ew[row * 64 + (c ^ ((row & 7) << 3))] = (bf16)(s[i][j][r] * inv);
      }
    }
  LGKM0; SCHED0;
  // 5) PV: pa from LDS, v from registers
  f32x4 o[4][2] = {};
  #pragma unroll
  for (int kk = 0; kk < 2; ++kk)
    #pragma unroll
    for (int mi = 0; mi < 4; ++mi) {
      int ra = mi * 16 + lr;
      bf16x8 pa = *(const bf16x8*)(Ew + ra * 64 + ((kk * 32 + (lg << 3)) ^ ((ra & 7) << 3)));
      #pragma unroll
      for (int nj = 0; nj < 2; ++nj)
        o[mi][nj] = __builtin_amdgcn_mfma_f32_16x16x32_bf16(pa, vf[kk][nj], o[mi][nj], 0, 0, 0);
    }
  // 6) ao rows (K-contiguous for out-proj)
  bf16* dst = ao + ((size_t)(mt * 128 + ww * 64)) * 512 + h * 32;
  #pragma unroll
  for (int mi = 0; mi < 4; ++mi)
    #pragma unroll
    for (int r = 0; r < 4; ++r) {
      int t = mi * 16 + (lg << 2) + r;
      #pragma unroll
      for (int nj = 0; nj < 2; ++nj)
        dst[(size_t)t * 512 + nj * 16 + lr] = (bf16)o[mi][nj][r];
    }
}

// ---------------- out-proj GEMM + bias + inverse roll ----------------
__global__ __launch_bounds__(256, 3) void gemm_out(
    const bf16* __restrict__ ao, const bf16* __restrict__ wob,
    const float* __restrict__ bout, float* __restrict__ out) {
  __shared__ bf16 SA[2][8192];
  bf16* SA0 = SA[0]; bf16* SA1 = SA[1];

  const int tid = threadIdx.x, wave = tid >> 6, lane = tid & 63;
  int bid = blockIdx.x;
  bid = (bid & 7) * 256 + (bid >> 3);          // XCD swizzle (2048 = 8*256)
  const int mt = bid >> 2, nt = bid & 3;
  const bf16* Ag = ao + ((size_t)mt * 128) * 512;
  const int wr = (wave >> 1) << 6, wc = (wave & 1) << 6;
  const int lr = lane & 15, lg = lane >> 4;
  const bf16* Bptr = wob + (((size_t)lg * 512) + nt * 128 + wc + lr) * 8;

  KLOOP_BD(Ag, 512)

  float bv[4];
  #pragma unroll
  for (int j = 0; j < 4; ++j) bv[j] = bout[nt * 128 + wc + j * 16 + lr];
  #pragma unroll
  for (int i = 0; i < 4; ++i)
    #pragma unroll
    for (int r = 0; r < 4; ++r) {
      int m = (mt << 7) + wr + i * 16 + (lg << 2) + r;
      int b = m >> 12, win = (m >> 6) & 63, t = m & 63;
      int ip = ((win >> 3) << 3) + (t >> 3);
      int jp = ((win & 7) << 3) + (t & 7);
      int io = (ip + 4) & 63, jo = (jp + 4) & 63;
      float* orow = out + ((((size_t)(b << 6) + io) << 6) + jo) * 512 + nt * 128 + wc;
      #pragma unroll
      for (int j = 0; j < 4; ++j)
        orow[j * 16 + lr] = acc[i][j][r] + bv[j];
    }
}

extern "C" void kernel_launch(void* const* d_in, const int* in_sizes, int n_in,
                              void* d_out, int out_size, void* d_ws, size_t ws_size,
                              hipStream_t stream) {
  const float* x    = (const float*)d_in[0];
  const float* wqkv = (const float*)d_in[1];
  const float* pos  = (const float*)d_in[2];
  const float* wout = (const float*)d_in[3];
  const float* bout = (const float*)d_in[4];
  float* out = (float*)d_out;

  char* ws = (char*)d_ws;
  bf16* xs      = (bf16*)(ws);                 // 64 MB
  bf16* ao      = (bf16*)(ws + 67108864);      // 64 MB
  bf16* wqkv_bt = (bf16*)(ws + 268435456);
  bf16* wout_bt = (bf16*)(ws + 270008320);
  float* bias4  = (float*)(ws + 270532608);

  prep_x<<<dim3(8192), dim3(256), 0, stream>>>(x, xs);
  prep_w<<<dim3(256), dim3(256), 0, stream>>>(wqkv, wout, wqkv_bt, wout_bt);
  prep_bias<<<dim3(1), dim3(256), 0, stream>>>(pos, bias4);
  qkv_attn<<<dim3(4096), dim3(256), 0, stream>>>(xs, wqkv_bt, bias4, ao);
  gemm_out<<<dim3(2048), dim3(256), 0, stream>>>(ao, wout_bt, bout, out);
}

// Round 10
// 250.950 us; speedup vs baseline: 6.4360x; 1.0432x over previous
//
#include <hip/hip_runtime.h>
#include <hip/hip_bf16.h>
#include <stdint.h>

typedef __bf16 bf16;
typedef __attribute__((ext_vector_type(4))) float f32x4;
typedef __attribute__((ext_vector_type(8))) bf16 bf16x8;
typedef __attribute__((ext_vector_type(4))) bf16 bf16x4;

#define AS1 __attribute__((address_space(1)))
#define AS3 __attribute__((address_space(3)))

static __device__ __forceinline__ void gload_lds16(const bf16* g, bf16* l) {
  __builtin_amdgcn_global_load_lds((const AS1 void*)g, (AS3 void*)l, 16, 0, 0);
}

#define BAR __builtin_amdgcn_s_barrier()
#define SCHED0 __builtin_amdgcn_sched_barrier(0)
#define VMC_(n) asm volatile("s_waitcnt vmcnt(" #n ")" ::: "memory")
#define VMC(n) VMC_(n)
#define LGKM_(n) asm volatile("s_waitcnt lgkmcnt(" #n ")" ::: "memory")
#define LGKM(n) LGKM_(n)
#define LGKM0 LGKM(0)

// ---- 256-thread staging: one 128x64 bf16 tile, 4 chunks/thread ----
#define STAGE_A(gsrc, dst, kt_) do {                                          \
  _Pragma("unroll") for (int s_ = 0; s_ < 4; ++s_) {                          \
    int idx_ = s_ * 256 + tid;                                                \
    int r_ = idx_ >> 3, c_ = idx_ & 7;                                        \
    gload_lds16((gsrc) + (size_t)r_ * 512 + ((kt_) << 6) + ((c_ ^ (r_ & 7)) << 3), \
                (dst) + idx_ * 8);                                            \
  }                                                                           \
} while (0)

// B fragments from L2 (K-major layout bt[k/8][col][8]); 4 col-blocks (gemm_out)
#define LOADB(ktq, NCOLX) do {                                                \
  const bf16* bp_ = Bptr + (size_t)(ktq) * ((size_t)(NCOLX) * 64);            \
  _Pragma("unroll") for (int cb_ = 0; cb_ < 4; ++cb_)                         \
  _Pragma("unroll") for (int ks_ = 0; ks_ < 2; ++ks_)                         \
    bfr[cb_][ks_] = *(const bf16x8*)(bp_ + cb_ * 128 + (size_t)ks_ * (NCOLX) * 32); \
} while (0)

// gemm_out K-loop (round-6, verified): A dbuf in LDS, B in regs from L2.
#define KLOOP_BD(Ag, NCOLX)                                                   \
  f32x4 acc[4][4] = {};                                                       \
  bf16x8 af[4][2], bfr[4][2];                                                 \
  STAGE_A(Ag, SA0, 0);                                                        \
  LOADB(0, NCOLX);                                                            \
  VMC(8); BAR;                                                                \
  STAGE_A(Ag, SA1, 1);                                                        \
  _Pragma("unroll 2")                                                         \
  for (int kt = 0; kt < 8; ++kt) {                                            \
    bf16* Ap = (kt & 1) ? SA1 : SA0;                                          \
    _Pragma("unroll") for (int i_ = 0; i_ < 4; ++i_) {                        \
      int ra_ = wr + i_ * 16 + lr;                                            \
      _Pragma("unroll") for (int ks_ = 0; ks_ < 2; ++ks_)                     \
        af[i_][ks_] = *(const bf16x8*)(Ap + ra_ * 64 + (((ks_ * 4 + lg) ^ (ra_ & 7)) << 3)); \
    }                                                                         \
    LGKM0; SCHED0;                                                            \
    __builtin_amdgcn_s_setprio(1);                                            \
    _Pragma("unroll") for (int i_ = 0; i_ < 4; ++i_)                          \
    _Pragma("unroll") for (int j_ = 0; j_ < 4; ++j_)                          \
    _Pragma("unroll") for (int ks_ = 0; ks_ < 2; ++ks_)                       \
      acc[i_][j_] = __builtin_amdgcn_mfma_f32_16x16x32_bf16(                  \
          af[i_][ks_], bfr[j_][ks_], acc[i_][j_], 0, 0, 0);                   \
    __builtin_amdgcn_s_setprio(0);                                            \
    if (kt < 7) LOADB(kt + 1, NCOLX);                                         \
    if (kt < 7) { VMC(8); }                                                   \
    BAR;                                                                      \
    if (kt < 6) STAGE_A(Ag, Ap, kt + 2);                                      \
  }

// ---------------- prep: roll + reorder + fp32->bf16 ----------------
__global__ __launch_bounds__(256) void prep_x(const float* __restrict__ x,
                                              bf16* __restrict__ xs) {
  int m = blockIdx.x * 8 + (threadIdx.x >> 5);
  int lane = threadIdx.x & 31;
  int b = m >> 12, win = (m >> 6) & 63, t = m & 63;
  int ip = ((win >> 3) << 3) + (t >> 3);
  int jp = ((win & 7) << 3) + (t & 7);
  int io = (ip + 4) & 63, jo = (jp + 4) & 63;
  const float* src = x + ((((size_t)(b << 6) + io) << 6) + jo) * 512;
  bf16* dst = xs + ((size_t)m << 9);
  #pragma unroll
  for (int c0 = 0; c0 < 512; c0 += 128) {
    int c = c0 + lane * 4;
    float4 v = *(const float4*)(src + c);
    bf16x4 o = { (bf16)v.x, (bf16)v.y, (bf16)v.z, (bf16)v.w };
    *(bf16x4*)(dst + c) = o;
  }
}

// Weights -> bf16, K-major-grouped bt[k/8][col][8]. q-scale folded.
// wqkv cols permuted head-major: col2 = h*96 + part*32 + d. wout unpermuted.
__global__ __launch_bounds__(256) void prep_w(const float* __restrict__ wqkv,
                                              const float* __restrict__ wout,
                                              bf16* __restrict__ wqkv_bt,
                                              bf16* __restrict__ wout_bt) {
  int r = blockIdx.x * 8 + (threadIdx.x >> 5);
  int lane = threadIdx.x & 31;
  const float* src;
  bf16* dstb;
  int ncol, col;
  float sc = 1.0f;
  if (r < 1536) {
    int part = r >> 9, h = (r >> 5) & 15, d = r & 31;
    src = wqkv + (size_t)r * 512; dstb = wqkv_bt; ncol = 1536;
    col = h * 96 + part * 32 + d;
    if (part == 0) sc = 0.17677669529663689f;
  } else {
    src = wout + (size_t)(r - 1536) * 512; dstb = wout_bt; ncol = 512; col = r - 1536;
  }
  #pragma unroll
  for (int kb = lane; kb < 64; kb += 32) {
    float4 v0 = *(const float4*)(src + kb * 8);
    float4 v1 = *(const float4*)(src + kb * 8 + 4);
    bf16x8 o = { (bf16)(v0.x * sc), (bf16)(v0.y * sc), (bf16)(v0.z * sc), (bf16)(v0.w * sc),
                 (bf16)(v1.x * sc), (bf16)(v1.y * sc), (bf16)(v1.z * sc), (bf16)(v1.w * sc) };
    *(bf16x8*)(dstb + ((size_t)kb * ncol + col) * 8) = o;
  }
}

__global__ __launch_bounds__(256) void prep_bias(const float* __restrict__ pos,
                                                 float* __restrict__ bias4) {
  for (int idx = threadIdx.x; idx < 4 * 4096; idx += 256) {
    int ty = idx >> 12, ij = idx & 4095;
    int i = ij >> 6, j = ij & 63;
    int rx = ((j >> 3) - (i >> 3)) + 7;
    int ry = ((j & 7) - (i & 7)) + 7;
    float v = pos[rx * 15 + ry];
    if ((ty & 1) && (((i ^ j) >> 5) & 1)) v = -1e30f;
    if ((ty & 2) && (((i ^ j) >> 2) & 1)) v = -1e30f;
    bias4[idx] = v;
  }
}

// ---- qkv_attn K-loop pieces (4-ring A, af dbuf, B half-dbuf) ----
#define SR(s) (smb + (s) * 8192)

#define STAGE_R(slot, kt_) STAGE_A(Ag, SR(slot), kt_)

#define RD_AF(dst, sptr) do {                                                 \
  _Pragma("unroll") for (int i_ = 0; i_ < 4; ++i_) {                          \
    int ra_ = ww * 64 + i_ * 16 + lr;                                         \
    _Pragma("unroll") for (int ks_ = 0; ks_ < 2; ++ks_)                       \
      dst[i_][ks_] = *(const bf16x8*)((sptr) + ra_ * 64 + (((ks_ * 4 + lg) ^ (ra_ & 7)) << 3)); \
  }                                                                           \
} while (0)

#define LOADB_H(set, ktq, hf) do {                                            \
  const bf16* bp_ = Bptr + (size_t)(ktq) * 98304 + (hf) * 384;                \
  _Pragma("unroll") for (int cb_ = 0; cb_ < 3; ++cb_)                         \
  _Pragma("unroll") for (int ks_ = 0; ks_ < 2; ++ks_)                         \
    set[cb_][ks_] = *(const bf16x8*)(bp_ + cb_ * 128 + ks_ * 49152);          \
} while (0)

#define MMP(afs, bs, j0)                                                      \
  _Pragma("unroll") for (int i_ = 0; i_ < 4; ++i_)                            \
  _Pragma("unroll") for (int jj_ = 0; jj_ < 3; ++jj_)                         \
  _Pragma("unroll") for (int ks_ = 0; ks_ < 2; ++ks_)                         \
    acc[i_][(j0) + jj_] = __builtin_amdgcn_mfma_f32_16x16x32_bf16(            \
        afs[i_][ks_], bs[jj_][ks_], acc[i_][(j0) + jj_], 0, 0, 0);

// Per-kt body. Publish discipline (per-wave vm FIFO ledger, steady state):
// top-of-kt queue [st(kt+2):4, h0(kt):6, h1(kt):6]; CN drains st+h0, FN drains h1.
#define KT_BODY(CUR, NXT, KT, CN, FN, LN) do {                                \
  if ((KT) < 7) RD_AF(NXT, SR(((KT) + 1) & 3));                               \
  if ((KT) <= 4) STAGE_R(((KT) + 3) & 3, (KT) + 3);                           \
  VMC(CN); LGKM(LN); SCHED0;                                                  \
  __builtin_amdgcn_s_setprio(1); MMP(CUR, bfrX, 0);                           \
  __builtin_amdgcn_s_setprio(0);                                              \
  if ((KT) < 7) LOADB_H(bfrX, (KT) + 1, 0);                                   \
  VMC(FN); SCHED0;                                                            \
  __builtin_amdgcn_s_setprio(1); MMP(CUR, bfrY, 3);                           \
  __builtin_amdgcn_s_setprio(0);                                              \
  if ((KT) < 7) LOADB_H(bfrY, (KT) + 1, 1);                                   \
  if ((KT) < 7) BAR;                                                          \
} while (0)

// ---------------- fused QKV-GEMM + window attention ----------------
// Block: 128 tokens (2 win) x 2 heads; 4 waves = 4 (win,head) units.
// A: 4-deep LDS ring (64KB), staged 2 kt ahead, ONE barrier per kt.
// af: double-buffered regs (ds latency hidden under MFMA).
// B: two half-buffers (h0/h1), each prefetched under the opposite half's MFMA.
// Epilogue (r9-verified): q|k via swizzled LDS E (unions ring slots 0/1 --
// untouched after kt4), v via same-lr shuffles, P reuses E.
__global__ __launch_bounds__(256, 2) void qkv_attn(
    const bf16* __restrict__ xs, const bf16* __restrict__ wb2,
    const float* __restrict__ bias4, bf16* __restrict__ ao) {
  __shared__ bf16 smb[32768];                  // 64 KB: ring 4x16KB; E = first 32KB

  const int tid = threadIdx.x, wave = tid >> 6, lane = tid & 63;
  const int ww = wave & 1, wh = wave >> 1;     // window-in-tile, head-in-pair
  const int lr = lane & 15, lg = lane >> 4;

  int bid = blockIdx.x;
  bid = (bid & 7) * 512 + (bid >> 3);          // XCD swizzle (4096 = 8*512)
  const int mt = bid >> 3, hp = bid & 7;
  const int h = hp * 2 + wh;

  const bf16* Ag = xs + ((size_t)mt * 128) * 512;
  const bf16* Bptr = wb2 + (((size_t)lg * 1536) + h * 96 + lr) * 8;

  f32x4 acc[4][6] = {};
  bf16x8 afA[4][2], afB[4][2], bfrX[3][2], bfrY[3][2];

  // prologue: stage A(0..2) into slots 0..2; load B(0) halves; publish 0,1.
  STAGE_R(0, 0); STAGE_R(1, 1); STAGE_R(2, 2);
  LOADB_H(bfrX, 0, 0); LOADB_H(bfrY, 0, 1);
  VMC(16); BAR;                                // drain st0,st1 -> publish
  RD_AF(afA, SR(0));

  KT_BODY(afA, afB, 0, 10, 10, 8);
  KT_BODY(afB, afA, 1, 10, 10, 8);
  KT_BODY(afA, afB, 2, 10, 10, 8);
  KT_BODY(afB, afA, 3, 10, 10, 8);
  KT_BODY(afA, afB, 4, 10, 10, 8);
  KT_BODY(afB, afA, 5, 6, 6, 8);
  KT_BODY(afA, afB, 6, 6, 6, 8);
  KT_BODY(afB, afA, 7, 6, 0, 0);

  // ---- per-wave epilogue (identical to r9) ----
  bf16* Ew = smb + wave * 4096;
  #pragma unroll
  for (int i = 0; i < 4; ++i)
    #pragma unroll
    for (int r = 0; r < 4; ++r) {
      int row = i * 16 + (lg << 2) + r;
      #pragma unroll
      for (int j = 0; j < 4; ++j) {
        int c = j * 16 + lr;
        Ew[row * 64 + (c ^ ((row & 7) << 3))] = (bf16)acc[i][j][r];
      }
    }
  bf16x8 vf[2][2];
  {
    const int s0 = lr + 16 * ((2 * lg) & 3);
    const int s1 = lr + 16 * ((2 * lg + 1) & 3);
    const bool lo = (lg < 2);
    #pragma unroll
    for (int kk = 0; kk < 2; ++kk)
      #pragma unroll
      for (int nj = 0; nj < 2; ++nj) {
        float f[8];
        #pragma unroll
        for (int c = 0; c < 4; ++c) {
          float a0 = __shfl(acc[2 * kk][4 + nj][c], s0);
          float a1 = __shfl(acc[2 * kk + 1][4 + nj][c], s0);
          f[c] = lo ? a0 : a1;
          float b0 = __shfl(acc[2 * kk][4 + nj][c], s1);
          float b1 = __shfl(acc[2 * kk + 1][4 + nj][c], s1);
          f[4 + c] = lo ? b0 : b1;
        }
        vf[kk][nj] = (bf16x8){ (bf16)f[0], (bf16)f[1], (bf16)f[2], (bf16)f[3],
                               (bf16)f[4], (bf16)f[5], (bf16)f[6], (bf16)f[7] };
      }
  }
  LGKM0; SCHED0;
  bf16x8 qf[4], kf[4];
  #pragma unroll
  for (int i = 0; i < 4; ++i) {
    int ra = i * 16 + lr;
    qf[i] = *(const bf16x8*)(Ew + ra * 64 + (((lg << 3)) ^ ((ra & 7) << 3)));
    kf[i] = *(const bf16x8*)(Ew + ra * 64 + ((32 + (lg << 3)) ^ ((ra & 7) << 3)));
  }
  f32x4 s[4][4] = {};
  #pragma unroll
  for (int i = 0; i < 4; ++i)
    #pragma unroll
    for (int j = 0; j < 4; ++j)
      s[i][j] = __builtin_amdgcn_mfma_f32_16x16x32_bf16(qf[i], kf[j], s[i][j], 0, 0, 0);

  const int gw = mt * 2 + ww;
  const int win = gw & 63;
  const int ty = ((win >= 56) ? 1 : 0) | (((win & 7) == 7) ? 2 : 0);
  const float* bt = bias4 + ty * 4096;
  #pragma unroll
  for (int i = 0; i < 4; ++i)
    #pragma unroll
    for (int r = 0; r < 4; ++r) {
      int row = i * 16 + (lg << 2) + r;
      #pragma unroll
      for (int j = 0; j < 4; ++j)
        s[i][j][r] += bt[row * 64 + j * 16 + lr];
    }
  #pragma unroll
  for (int i = 0; i < 4; ++i)
    #pragma unroll
    for (int r = 0; r < 4; ++r) {
      float mx = fmaxf(fmaxf(s[i][0][r], s[i][1][r]), fmaxf(s[i][2][r], s[i][3][r]));
      mx = fmaxf(mx, __shfl_xor(mx, 1));
      mx = fmaxf(mx, __shfl_xor(mx, 2));
      mx = fmaxf(mx, __shfl_xor(mx, 4));
      mx = fmaxf(mx, __shfl_xor(mx, 8));
      float sum = 0.f;
      #pragma unroll
      for (int j = 0; j < 4; ++j) { s[i][j][r] = __expf(s[i][j][r] - mx); sum += s[i][j][r]; }
      sum += __shfl_xor(sum, 1);
      sum += __shfl_xor(sum, 2);
      sum += __shfl_xor(sum, 4);
      sum += __shfl_xor(sum, 8);
      float inv = 1.0f / sum;
      int row = i * 16 + (lg << 2) + r;
      #pragma unroll
      for (int j = 0; j < 4; ++j) {
        int c = j * 16 + lr;
        Ew[row * 64 + (c ^ ((row & 7) << 3))] = (bf16)(s[i][j][r] * inv);
      }
    }
  LGKM0; SCHED0;
  f32x4 o[4][2] = {};
  #pragma unroll
  for (int kk = 0; kk < 2; ++kk)
    #pragma unroll
    for (int mi = 0; mi < 4; ++mi) {
      int ra = mi * 16 + lr;
      bf16x8 pa = *(const bf16x8*)(Ew + ra * 64 + ((kk * 32 + (lg << 3)) ^ ((ra & 7) << 3)));
      #pragma unroll
      for (int nj = 0; nj < 2; ++nj)
        o[mi][nj] = __builtin_amdgcn_mfma_f32_16x16x32_bf16(pa, vf[kk][nj], o[mi][nj], 0, 0, 0);
    }
  bf16* dst = ao + ((size_t)(mt * 128 + ww * 64)) * 512 + h * 32;
  #pragma unroll
  for (int mi = 0; mi < 4; ++mi)
    #pragma unroll
    for (int r = 0; r < 4; ++r) {
      int t = mi * 16 + (lg << 2) + r;
      #pragma unroll
      for (int nj = 0; nj < 2; ++nj)
        dst[(size_t)t * 512 + nj * 16 + lr] = (bf16)o[mi][nj][r];
    }
}

// ---------------- out-proj GEMM + bias + inverse roll ----------------
__global__ __launch_bounds__(256, 3) void gemm_out(
    const bf16* __restrict__ ao, const bf16* __restrict__ wob,
    const float* __restrict__ bout, float* __restrict__ out) {
  __shared__ bf16 SA[2][8192];
  bf16* SA0 = SA[0]; bf16* SA1 = SA[1];

  const int tid = threadIdx.x, wave = tid >> 6, lane = tid & 63;
  int bid = blockIdx.x;
  bid = (bid & 7) * 256 + (bid >> 3);          // XCD swizzle (2048 = 8*256)
  const int mt = bid >> 2, nt = bid & 3;
  const bf16* Ag = ao + ((size_t)mt * 128) * 512;
  const int wr = (wave >> 1) << 6, wc = (wave & 1) << 6;
  const int lr = lane & 15, lg = lane >> 4;
  const bf16* Bptr = wob + (((size_t)lg * 512) + nt * 128 + wc + lr) * 8;

  KLOOP_BD(Ag, 512)

  float bv[4];
  #pragma unroll
  for (int j = 0; j < 4; ++j) bv[j] = bout[nt * 128 + wc + j * 16 + lr];
  #pragma unroll
  for (int i = 0; i < 4; ++i)
    #pragma unroll
    for (int r = 0; r < 4; ++r) {
      int m = (mt << 7) + wr + i * 16 + (lg << 2) + r;
      int b = m >> 12, win = (m >> 6) & 63, t = m & 63;
      int ip = ((win >> 3) << 3) + (t >> 3);
      int jp = ((win & 7) << 3) + (t & 7);
      int io = (ip + 4) & 63, jo = (jp + 4) & 63;
      float* orow = out + ((((size_t)(b << 6) + io) << 6) + jo) * 512 + nt * 128 + wc;
      #pragma unroll
      for (int j = 0; j < 4; ++j)
        orow[j * 16 + lr] = acc[i][j][r] + bv[j];
    }
}

extern "C" void kernel_launch(void* const* d_in, const int* in_sizes, int n_in,
                              void* d_out, int out_size, void* d_ws, size_t ws_size,
                              hipStream_t stream) {
  const float* x    = (const float*)d_in[0];
  const float* wqkv = (const float*)d_in[1];
  const float* pos  = (const float*)d_in[2];
  const float* wout = (const float*)d_in[3];
  const float* bout = (const float*)d_in[4];
  float* out = (float*)d_out;

  char* ws = (char*)d_ws;
  bf16* xs      = (bf16*)(ws);                 // 64 MB
  bf16* ao      = (bf16*)(ws + 67108864);      // 64 MB
  bf16* wqkv_bt = (bf16*)(ws + 268435456);
  bf16* wout_bt = (bf16*)(ws + 270008320);
  float* bias4  = (float*)(ws + 270532608);

  prep_x<<<dim3(8192), dim3(256), 0, stream>>>(x, xs);
  prep_w<<<dim3(256), dim3(256), 0, stream>>>(wqkv, wout, wqkv_bt, wout_bt);
  prep_bias<<<dim3(1), dim3(256), 0, stream>>>(pos, bias4);
  qkv_attn<<<dim3(4096), dim3(256), 0, stream>>>(xs, wqkv_bt, bias4, ao);
  gemm_out<<<dim3(2048), dim3(256), 0, stream>>>(ao, wout_bt, bout, out);
}